// Round 15
// baseline (422.517 us; speedup 1.0000x reference)
//
#include <hip/hip_runtime.h>

#define KDIM   128
#define NELEM  8388608

typedef __attribute__((ext_vector_type(4))) float f32x4;
typedef __attribute__((ext_vector_type(2))) int   int2v;

__device__ inline f32x4 mfma8(long long a, long long b, f32x4 c) {
  return __builtin_amdgcn_mfma_f32_16x16x32_fp8_fp8(a, b, c, 0, 0, 0);
}
__device__ inline void gload16(const void* g, void* l) {
  __builtin_amdgcn_global_load_lds(
      (const __attribute__((address_space(1))) unsigned*)g,
      (__attribute__((address_space(3))) unsigned*)l, 16, 0, 0);
}
__device__ inline long long pk8(float4 v0, float4 v1) {
  int lo = __builtin_amdgcn_cvt_pk_fp8_f32(v0.x, v0.y, 0, false);
  lo     = __builtin_amdgcn_cvt_pk_fp8_f32(v0.z, v0.w, lo, true);
  int hi = __builtin_amdgcn_cvt_pk_fp8_f32(v1.x, v1.y, 0, false);
  hi     = __builtin_amdgcn_cvt_pk_fp8_f32(v1.z, v1.w, hi, true);
  int2v t; t.x = lo; t.y = hi;
  return __builtin_bit_cast(long long, t);
}
__device__ inline float packk(float s, int c) {
  return __builtin_bit_cast(float,
      (__builtin_bit_cast(unsigned, s) & 0xFFFFFC00u) | (unsigned)c);
}
__device__ inline float sumsq(float4 a, float4 b) {
  return a.x*a.x + a.y*a.y + a.z*a.z + a.w*a.w + b.x*b.x + b.y*b.y + b.z*b.z + b.w*b.w;
}
__device__ inline void merge8(float (&t)[8], int msk) {
  float o[8];
#pragma unroll
  for (int p = 0; p < 8; ++p) o[p] = __shfl_xor(t[p], msk);
  float m[8];
#pragma unroll
  for (int p = 0; p < 8; ++p) m[p] = fmaxf(t[p], o[7 - p]);
#pragma unroll
  for (int s = 4; s; s >>= 1)
#pragma unroll
    for (int i = 0; i < 8; ++i)
      if (!(i & s)) {
        float x = fmaxf(m[i], m[i | s]);
        m[i | s] = fminf(m[i], m[i | s]);
        m[i] = x;
      }
#pragma unroll
  for (int p = 0; p < 8; ++p) t[p] = m[p];
}
__device__ inline void ins8(float (&top)[8], float x) {
#pragma unroll
  for (int p = 0; p < 8; ++p) {
    float mx = fmaxf(top[p], x);
    x = fminf(top[p], x);
    top[p] = mx;
  }
}

struct Frags { long long b0[4], b1[4]; float fsq0, fsq1; };

__device__ inline Frags make_frags(const float* __restrict__ lat, int row0, int row1,
                                   int n, int hi) {
  const float* rp0 = lat + (size_t)(row0 + n) * KDIM + hi * 8;
  const float* rp1 = lat + (size_t)(row1 + n) * KDIM + hi * 8;
  float4 p0[4], p1[4], q0[4], q1[4];
#pragma unroll
  for (int ks = 0; ks < 4; ++ks) {
    p0[ks] = *(const float4*)(rp0 + ks * 32);
    p1[ks] = *(const float4*)(rp0 + ks * 32 + 4);
    q0[ks] = *(const float4*)(rp1 + ks * 32);
    q1[ks] = *(const float4*)(rp1 + ks * 32 + 4);
  }
  Frags f;
  float s0 = 0.f, s1 = 0.f;
#pragma unroll
  for (int ks = 0; ks < 4; ++ks) { s0 += sumsq(p0[ks], p1[ks]); s1 += sumsq(q0[ks], q1[ks]); }
  s0 += __shfl_xor(s0, 16); s0 += __shfl_xor(s0, 32);
  s1 += __shfl_xor(s1, 16); s1 += __shfl_xor(s1, 32);
  f.fsq0 = s0; f.fsq1 = s1;
#pragma unroll
  for (int ks = 0; ks < 4; ++ks) {
    f.b0[ks] = pk8(p0[ks], p1[ks]);
    f.b1[ks] = pk8(q0[ks], q1[ks]);
  }
  return f;
}

__device__ inline void dma_codebook(const unsigned char* __restrict__ ebf8,
                                    const float* __restrict__ esqm,
                                    unsigned char* smem, float* esqmLds, int tid) {
  const char* src = (const char*)ebf8 + tid * 16;
  char* dst = (char*)smem + tid * 16;
#pragma unroll
  for (int qq = 0; qq < 16; ++qq) gload16(src + qq * 8192, dst + qq * 8192);
  if (tid < 256) gload16((const char*)esqm + tid * 16, (char*)esqmLds + tid * 16);
}

template <bool SEL>
__device__ inline void scan_loop(const unsigned char* bk0, const unsigned char* bk1,
                                 const unsigned char* bk2, const unsigned char* bk3,
                                 const float* esqmLds, int hi, int wid, const Frags& f,
                                 float (&top0)[8], float (&top1)[8]) {
  const int stw = wid * 4;
#pragma unroll 4
  for (int pp = 0; pp < 32; ++pp) {
    const int g = (pp + stw) & 31;
    const int off = g * 4096;
    const float* eb = esqmLds + g * 32 + hi * 4;
    f32x4 e0 = *(const f32x4*)(eb);
    f32x4 e1 = *(const f32x4*)(eb + 16);
    long long t0 = *(const long long*)(bk0 + off);
    long long t1 = *(const long long*)(bk1 + off);
    long long t2 = *(const long long*)(bk2 + off);
    long long t3 = *(const long long*)(bk3 + off);
    long long u0 = *(const long long*)(bk0 + off + 2048);
    long long u1 = *(const long long*)(bk1 + off + 2048);
    long long u2 = *(const long long*)(bk2 + off + 2048);
    long long u3 = *(const long long*)(bk3 + off + 2048);
    f32x4 a0 = e0, a1 = e1, a2 = e0, a3 = e1;
    a0 = mfma8(t0, f.b0[0], a0); a1 = mfma8(u0, f.b0[0], a1);
    a2 = mfma8(t0, f.b1[0], a2); a3 = mfma8(u0, f.b1[0], a3);
    a0 = mfma8(t1, f.b0[1], a0); a1 = mfma8(u1, f.b0[1], a1);
    a2 = mfma8(t1, f.b1[1], a2); a3 = mfma8(u1, f.b1[1], a3);
    a0 = mfma8(t2, f.b0[2], a0); a1 = mfma8(u2, f.b0[2], a1);
    a2 = mfma8(t2, f.b1[2], a2); a3 = mfma8(u2, f.b1[2], a3);
    a0 = mfma8(t3, f.b0[3], a0); a1 = mfma8(u3, f.b0[3], a1);
    a2 = mfma8(t3, f.b1[3], a2); a3 = mfma8(u3, f.b1[3], a3);
    if constexpr (!SEL) {
      asm volatile("" :: "v"(a0[0]), "v"(a0[1]), "v"(a0[2]), "v"(a0[3]),
                        "v"(a1[0]), "v"(a1[1]), "v"(a1[2]), "v"(a1[3]),
                        "v"(a2[0]), "v"(a2[1]), "v"(a2[2]), "v"(a2[3]),
                        "v"(a3[0]), "v"(a3[1]), "v"(a3[2]), "v"(a3[3]));
    } else {
      const int cb = g * 32 + hi * 4;
      {
        float k0 = packk(a0[0], cb + 0),  k1 = packk(a0[1], cb + 1);
        float k2 = packk(a0[2], cb + 2),  k3 = packk(a0[3], cb + 3);
        float k4 = packk(a1[0], cb + 16), k5 = packk(a1[1], cb + 17);
        float k6 = packk(a1[2], cb + 18), k7 = packk(a1[3], cb + 19);
        ins8(top0, fmaxf(fmaxf(fmaxf(k0, k1), fmaxf(k2, k3)),
                         fmaxf(fmaxf(k4, k5), fmaxf(k6, k7))));
      }
      {
        float k0 = packk(a2[0], cb + 0),  k1 = packk(a2[1], cb + 1);
        float k2 = packk(a2[2], cb + 2),  k3 = packk(a2[3], cb + 3);
        float k4 = packk(a3[0], cb + 16), k5 = packk(a3[1], cb + 17);
        float k6 = packk(a3[2], cb + 18), k7 = packk(a3[3], cb + 19);
        ins8(top1, fmaxf(fmaxf(fmaxf(k0, k1), fmaxf(k2, k3)),
                         fmaxf(fmaxf(k4, k5), fmaxf(k6, k7))));
      }
    }
  }
}

__device__ inline void write_rows(const float* __restrict__ emb, float* __restrict__ outp,
                                  int grow0, int idx, int lane) {
#pragma unroll 4
  for (int r = 0; r < 16; ++r) {
    int s2 = __shfl(idx, r);
    float2 qv = *(const float2*)(emb + (size_t)s2 * KDIM + lane * 2);
    *(float2*)(outp + (size_t)(grow0 + r) * KDIM + lane * 2) = qv;
  }
}

// ---- prep (real) ----
__global__ void vq_prep(const float* __restrict__ emb, unsigned char* __restrict__ ebf8,
                        float* __restrict__ esqm, unsigned long long* __restrict__ lossAcc,
                        unsigned* __restrict__ cnt) {
  int j = blockIdx.x, d = threadIdx.x;
  float v = emb[j * KDIM + d];
  float vs = v * 1024.0f;
  int p = __builtin_amdgcn_cvt_pk_fp8_f32(vs, vs, 0, false);
  ebf8[j * KDIM + (d ^ ((j & 15) << 3))] = (unsigned char)(p & 0xFF);
  float s = v * v;
#pragma unroll
  for (int m = 1; m <= 32; m <<= 1) s += __shfl_xor(s, m);
  __shared__ float w[2];
  if ((d & 63) == 0) w[d >> 6] = s;
  __syncthreads();
  if (d == 0) esqm[j] = -512.0f * (w[0] + w[1]);
  if (j == 0 && d == 0) { lossAcc[0] = 0ULL; cnt[0] = 0u; }
}

// ---- diagnostics (each phase x8/x16, distinct names for rocprof) ----
__global__ __launch_bounds__(512, 1) void zz_lat(const float* __restrict__ lat) {
  const int tid = threadIdx.x, lane = tid & 63, wid = tid >> 6;
  const int n = lane & 15, hi = lane >> 4;
  const int gR0 = blockIdx.x * 256;
  for (int rep = 0; rep < 16; ++rep) {
    int base = ((gR0 + wid * 32 + rep * 2085) & 8191) & ~31;   // fresh 32-row window
    Frags f = make_frags(lat, base, base + 16, n, hi);
    asm volatile("" :: "v"(f.b0[0]), "v"(f.b0[1]), "v"(f.b0[2]), "v"(f.b0[3]),
                      "v"(f.b1[0]), "v"(f.b1[1]), "v"(f.b1[2]), "v"(f.b1[3]),
                      "v"(f.fsq0), "v"(f.fsq1));
    asm volatile("s_waitcnt vmcnt(0)" ::: "memory");
  }
}

__global__ __launch_bounds__(512, 1) void zz_dma(const unsigned char* __restrict__ ebf8,
                                                 const float* __restrict__ esqm) {
  __shared__ __align__(16) unsigned char smem[131072 + 4096];
  float* esqmLds = (float*)(smem + 131072);
  const int tid = threadIdx.x;
  for (int rep = 0; rep < 16; ++rep) {
    dma_codebook(ebf8, esqm, smem, esqmLds, tid);
    asm volatile("s_waitcnt vmcnt(0)" ::: "memory");
    __builtin_amdgcn_s_barrier();
  }
}

template <bool SEL>
__device__ inline void zz_scan_body(const float* lat, const unsigned char* ebf8,
                                    const float* esqm) {
  __shared__ __align__(16) unsigned char smem[131072 + 4096];
  float* esqmLds = (float*)(smem + 131072);
  const int tid = threadIdx.x, lane = tid & 63, wid = tid >> 6;
  const int n = lane & 15, hi = lane >> 4;
  const int gR0 = blockIdx.x * 256;
  Frags f = make_frags(lat, gR0 + wid * 32, gR0 + wid * 32 + 16, n, hi);
  dma_codebook(ebf8, esqm, smem, esqmLds, tid);
  asm volatile("s_waitcnt vmcnt(0)" ::: "memory");
  __builtin_amdgcn_s_barrier();
  const unsigned char* ab = smem + n * 128 + ((hi ^ (n & 3)) << 3);
  const int nh = n >> 2;
  const unsigned char* bk0 = ab + ((0 ^ nh) << 5);
  const unsigned char* bk1 = ab + ((1 ^ nh) << 5);
  const unsigned char* bk2 = ab + ((2 ^ nh) << 5);
  const unsigned char* bk3 = ab + ((3 ^ nh) << 5);
  const float NINF = __builtin_bit_cast(float, 0xFF800000u);
  float top0[8], top1[8];
#pragma unroll
  for (int p = 0; p < 8; ++p) { top0[p] = NINF; top1[p] = NINF; }
  for (int rep = 0; rep < 8; ++rep)
    scan_loop<SEL>(bk0, bk1, bk2, bk3, esqmLds, hi, wid, f, top0, top1);
  asm volatile("" :: "v"(top0[0]), "v"(top0[7]), "v"(top1[0]), "v"(top1[7]),
                    "v"(f.fsq0), "v"(f.fsq1));
}
__global__ __launch_bounds__(512, 1) void zz_scan(const float* __restrict__ lat,
    const unsigned char* __restrict__ ebf8, const float* __restrict__ esqm) {
  zz_scan_body<false>(lat, ebf8, esqm);
}
__global__ __launch_bounds__(512, 1) void zz_sel(const float* __restrict__ lat,
    const unsigned char* __restrict__ ebf8, const float* __restrict__ esqm) {
  zz_scan_body<true>(lat, ebf8, esqm);
}

__global__ __launch_bounds__(512, 1) void zz_wr(const float* __restrict__ lat,
    const unsigned char* __restrict__ ebf8, const float* __restrict__ esqm,
    const float* __restrict__ emb, const int* __restrict__ ksel,
    float* __restrict__ ws0, float* __restrict__ ws1) {
  __shared__ __align__(16) unsigned char smem[131072 + 4096];
  float* esqmLds = (float*)(smem + 131072);
  const int tid = threadIdx.x, lane = tid & 63, wid = tid >> 6;
  const int n = lane & 15, hi = lane >> 4;
  const int gR0 = blockIdx.x * 256;
  Frags f = make_frags(lat, gR0 + wid * 32, gR0 + wid * 32 + 16, n, hi);
  dma_codebook(ebf8, esqm, smem, esqmLds, tid);
  asm volatile("s_waitcnt vmcnt(0)" ::: "memory");
  __builtin_amdgcn_s_barrier();
  const unsigned char* ab = smem + n * 128 + ((hi ^ (n & 3)) << 3);
  const int nh = n >> 2;
  const unsigned char* bk0 = ab + ((0 ^ nh) << 5);
  const unsigned char* bk1 = ab + ((1 ^ nh) << 5);
  const unsigned char* bk2 = ab + ((2 ^ nh) << 5);
  const unsigned char* bk3 = ab + ((3 ^ nh) << 5);
  const float NINF = __builtin_bit_cast(float, 0xFF800000u);
  float top0[8], top1[8];
#pragma unroll
  for (int p = 0; p < 8; ++p) { top0[p] = NINF; top1[p] = NINF; }
  scan_loop<true>(bk0, bk1, bk2, bk3, esqmLds, hi, wid, f, top0, top1);
  int kk = ksel[lane & 7]; kk = kk < 0 ? 0 : (kk > 7 ? 7 : kk);
  merge8(top0, 16); merge8(top0, 32);
  merge8(top1, 16); merge8(top1, 32);
  float sel0 = top0[0], sel1 = top1[0];
#pragma unroll
  for (int p = 1; p < 8; ++p) { sel0 = (kk == p) ? top0[p] : sel0; sel1 = (kk == p) ? top1[p] : sel1; }
  int idx0 = (int)(__builtin_bit_cast(unsigned, sel0) & 1023u);
  int idx1 = (int)(__builtin_bit_cast(unsigned, sel1) & 1023u);
  for (int rep = 0; rep < 16; ++rep) {   // x16 write tail into ws scratch
    float* w = (rep & 1) ? ws1 : ws0;
    write_rows(emb, w, gR0 + wid * 32, idx0, lane);
    write_rows(emb, w, gR0 + wid * 32 + 16, idx1, lane);
    asm volatile("s_waitcnt vmcnt(0)" ::: "memory");
  }
}

// ---- real main (r14 verbatim semantics) ----
__global__ __launch_bounds__(512, 1) void vq_main(
    const float* __restrict__ lat, const float* __restrict__ emb,
    const int* __restrict__ ksel, const unsigned char* __restrict__ ebf8,
    const float* __restrict__ esqm, float* __restrict__ out,
    unsigned long long* __restrict__ lossAcc, unsigned* __restrict__ cnt,
    float* __restrict__ loss) {
  __shared__ __align__(16) unsigned char smem[131072 + 4096 + 64];
  float* esqmLds = (float*)(smem + 131072);
  float* wLds    = (float*)(smem + 131072 + 4096);
  const int tid = threadIdx.x, lane = tid & 63, wid = tid >> 6;
  const int n = lane & 15, hi = lane >> 4;
  const int gR0 = blockIdx.x * 256;
  Frags f = make_frags(lat, gR0 + wid * 32, gR0 + wid * 32 + 16, n, hi);
  dma_codebook(ebf8, esqm, smem, esqmLds, tid);
  asm volatile("s_waitcnt vmcnt(0)" ::: "memory");
  __builtin_amdgcn_s_barrier();
  const unsigned char* ab = smem + n * 128 + ((hi ^ (n & 3)) << 3);
  const int nh = n >> 2;
  const unsigned char* bk0 = ab + ((0 ^ nh) << 5);
  const unsigned char* bk1 = ab + ((1 ^ nh) << 5);
  const unsigned char* bk2 = ab + ((2 ^ nh) << 5);
  const unsigned char* bk3 = ab + ((3 ^ nh) << 5);
  const float NINF = __builtin_bit_cast(float, 0xFF800000u);
  float top0[8], top1[8];
#pragma unroll
  for (int p = 0; p < 8; ++p) { top0[p] = NINF; top1[p] = NINF; }
  scan_loop<true>(bk0, bk1, bk2, bk3, esqmLds, hi, wid, f, top0, top1);

  int kk = ksel[lane & 7]; kk = kk < 0 ? 0 : (kk > 7 ? 7 : kk);
  merge8(top0, 16); merge8(top0, 32);
  float sel0 = top0[0];
#pragma unroll
  for (int p = 1; p < 8; ++p) sel0 = (kk == p) ? top0[p] : sel0;
  unsigned sb0 = __builtin_bit_cast(unsigned, sel0);
  int idx0 = (int)(sb0 & 1023u);
  float rl0 = f.fsq0 - __builtin_bit_cast(float, sb0 & 0xFFFFFC00u) * (1.0f / 512.0f);
  write_rows(emb, out, gR0 + wid * 32, idx0, lane);

  merge8(top1, 16); merge8(top1, 32);
  float sel1 = top1[0];
#pragma unroll
  for (int p = 1; p < 8; ++p) sel1 = (kk == p) ? top1[p] : sel1;
  unsigned sb1 = __builtin_bit_cast(unsigned, sel1);
  int idx1 = (int)(sb1 & 1023u);
  float rl1 = f.fsq1 - __builtin_bit_cast(float, sb1 & 0xFFFFFC00u) * (1.0f / 512.0f);
  write_rows(emb, out, gR0 + wid * 32 + 16, idx1, lane);

  float c = (lane < 16) ? (rl0 + rl1) : 0.f;
#pragma unroll
  for (int m = 1; m <= 32; m <<= 1) c += __shfl_xor(c, m);
  if (lane == 0) wLds[wid] = c;
  __syncthreads();
  if (tid == 0) {
    double bs = 0.0;
#pragma unroll
    for (int w = 0; w < 8; ++w) bs += (double)wLds[w];
    long long iv = (long long)(bs * 1048576.0 + 0.5);
    atomicAdd(lossAcc, (unsigned long long)iv);
    __threadfence();
    unsigned done = atomicAdd(cnt, 1u);
    if (done == 255u) {
      unsigned long long tot = atomicAdd(lossAcc, 0ULL);
      loss[0] = (float)((double)(long long)tot * (1.25 / (1048576.0 * 8388608.0)));
    }
  }
}

extern "C" void kernel_launch(void* const* d_in, const int* in_sizes, int n_in,
                              void* d_out, int out_size, void* d_ws, size_t ws_size,
                              hipStream_t stream) {
  const float* lat = (const float*)d_in[0];
  const float* emb = (const float*)d_in[1];
  const int* ksel = (const int*)d_in[2];
  float* out = (float*)d_out;

  unsigned char* ebf8 = (unsigned char*)d_ws;
  float* esqm = (float*)((char*)d_ws + 131072);
  unsigned long long* lossAcc = (unsigned long long*)((char*)d_ws + 135168);
  unsigned* cnt = (unsigned*)((char*)d_ws + 135176);
  float* ws0 = (float*)((char*)d_ws + (size_t)(16 << 20));   // 2x 32MB scratch for zz_wr
  float* ws1 = (float*)((char*)d_ws + (size_t)(80 << 20));

  vq_prep<<<1024, 128, 0, stream>>>(emb, ebf8, esqm, lossAcc, cnt);
  // diagnostics (named; each phase x8/x16 so it ranks above harness fills)
  zz_lat<<<256, 512, 0, stream>>>(lat);
  zz_dma<<<256, 512, 0, stream>>>(ebf8, esqm);
  zz_scan<<<256, 512, 0, stream>>>(lat, ebf8, esqm);
  zz_sel<<<256, 512, 0, stream>>>(lat, ebf8, esqm);
  zz_wr<<<256, 512, 0, stream>>>(lat, ebf8, esqm, emb, ksel, ws0, ws1);
  // real kernel (correct output)
  vq_main<<<256, 512, 0, stream>>>(lat, emb, ksel, ebf8, esqm, out, lossAcc, cnt,
                                   out + NELEM);
}

// Round 16
// 51.934 us; speedup vs baseline: 8.1357x; 8.1357x over previous
//
#include <hip/hip_runtime.h>

#define KDIM   128
#define NELEM  8388608

typedef __attribute__((ext_vector_type(4))) float f32x4;
typedef __attribute__((ext_vector_type(2))) int   int2v;

__device__ inline f32x4 mfma8(long long a, long long b, f32x4 c) {
  return __builtin_amdgcn_mfma_f32_16x16x32_fp8_fp8(a, b, c, 0, 0, 0);
}
__device__ inline void gload16(const void* g, void* l) {
  __builtin_amdgcn_global_load_lds(
      (const __attribute__((address_space(1))) unsigned*)g,
      (__attribute__((address_space(3))) unsigned*)l, 16, 0, 0);
}
__device__ inline long long pk8(float4 v0, float4 v1) {   // 8 fp32 -> 8 fp8 e4m3 (RNE)
  int lo = __builtin_amdgcn_cvt_pk_fp8_f32(v0.x, v0.y, 0, false);
  lo     = __builtin_amdgcn_cvt_pk_fp8_f32(v0.z, v0.w, lo, true);
  int hi = __builtin_amdgcn_cvt_pk_fp8_f32(v1.x, v1.y, 0, false);
  hi     = __builtin_amdgcn_cvt_pk_fp8_f32(v1.z, v1.w, hi, true);
  int2v t; t.x = lo; t.y = hi;
  return __builtin_bit_cast(long long, t);
}
__device__ inline float andor(float s, int c) {   // (score & ~1023) | lane-id  (1 VALU op)
  return __builtin_bit_cast(float,
      (__builtin_bit_cast(unsigned, s) & 0xFFFFFC00u) | (unsigned)c);
}
__device__ inline float sumsq(float4 a, float4 b) {
  return a.x*a.x + a.y*a.y + a.z*a.z + a.w*a.w + b.x*b.x + b.y*b.y + b.z*b.z + b.w*b.w;
}
__device__ inline void merge8(float (&t)[8], int msk) {   // bitonic top-8 of 16 across lanes
  float o[8];
#pragma unroll
  for (int p = 0; p < 8; ++p) o[p] = __shfl_xor(t[p], msk);
  float m[8];
#pragma unroll
  for (int p = 0; p < 8; ++p) m[p] = fmaxf(t[p], o[7 - p]);
#pragma unroll
  for (int s = 4; s; s >>= 1)
#pragma unroll
    for (int i = 0; i < 8; ++i)
      if (!(i & s)) {
        float x = fmaxf(m[i], m[i | s]);
        m[i | s] = fminf(m[i], m[i | s]);
        m[i] = x;
      }
#pragma unroll
  for (int p = 0; p < 8; ++p) t[p] = m[p];
}
__device__ inline void ins8(float (&top)[8], float x) {   // branchless desc top-8 insert
#pragma unroll
  for (int p = 0; p < 8; ++p) {
    float mx = fmaxf(top[p], x);
    x = fminf(top[p], x);
    top[p] = mx;
  }
}

struct Frags { long long b0[4], b1[4]; float fsq0, fsq1; };

__device__ inline Frags make_frags(const float* __restrict__ lat, int row0, int row1,
                                   int n, int hi) {
  const float* rp0 = lat + (size_t)(row0 + n) * KDIM + hi * 8;
  const float* rp1 = lat + (size_t)(row1 + n) * KDIM + hi * 8;
  float4 p0[4], p1[4], q0[4], q1[4];
#pragma unroll
  for (int ks = 0; ks < 4; ++ks) {
    p0[ks] = *(const float4*)(rp0 + ks * 32);
    p1[ks] = *(const float4*)(rp0 + ks * 32 + 4);
    q0[ks] = *(const float4*)(rp1 + ks * 32);
    q1[ks] = *(const float4*)(rp1 + ks * 32 + 4);
  }
  Frags f;
  float s0 = 0.f, s1 = 0.f;
#pragma unroll
  for (int ks = 0; ks < 4; ++ks) { s0 += sumsq(p0[ks], p1[ks]); s1 += sumsq(q0[ks], q1[ks]); }
  s0 += __shfl_xor(s0, 16); s0 += __shfl_xor(s0, 32);
  s1 += __shfl_xor(s1, 16); s1 += __shfl_xor(s1, 32);
  f.fsq0 = s0; f.fsq1 = s1;
#pragma unroll
  for (int ks = 0; ks < 4; ++ks) {
    f.b0[ks] = pk8(p0[ks], p1[ks]);
    f.b1[ks] = pk8(q0[ks], q1[ks]);
  }
  return f;
}

__device__ inline void write_rows(const float* __restrict__ emb, float* __restrict__ outp,
                                  int grow0, int idx, int lane) {
#pragma unroll 4
  for (int r = 0; r < 16; ++r) {
    int s2 = __shfl(idx, r);
    float2 qv = *(const float2*)(emb + (size_t)s2 * KDIM + lane * 2);
    *(float2*)(outp + (size_t)(grow0 + r) * KDIM + lane * 2) = qv;
  }
}

// ---- prep: emb -> fp8 (x1024, K-XOR-swizzled) + -512*||e||^2 + zero accumulators ----
__global__ void vq_prep(const float* __restrict__ emb, unsigned char* __restrict__ ebf8,
                        float* __restrict__ esqm, unsigned long long* __restrict__ lossAcc,
                        unsigned* __restrict__ cnt) {
  int j = blockIdx.x, d = threadIdx.x;
  float v = emb[j * KDIM + d];
  float vs = v * 1024.0f;
  int p = __builtin_amdgcn_cvt_pk_fp8_f32(vs, vs, 0, false);
  ebf8[j * KDIM + (d ^ ((j & 15) << 3))] = (unsigned char)(p & 0xFF);
  float s = v * v;
#pragma unroll
  for (int m = 1; m <= 32; m <<= 1) s += __shfl_xor(s, m);
  __shared__ float w[2];
  if ((d & 63) == 0) w[d >> 6] = s;
  __syncthreads();
  if (d == 0) esqm[j] = -512.0f * (w[0] + w[1]);   // score = 1024*(f.e - ||e||^2/2)
  if (j == 0 && d == 0) { lossAcc[0] = 0ULL; cnt[0] = 0u; }
}

// scan one 512-code half, all offsets compile-time (no stagger)
template <int H>
__device__ inline void scan_half(const unsigned char* smem, const float* esqmLds,
                                 int n, int hi, const Frags& f, const int (&c8)[8],
                                 float (&top0)[8], float (&top1)[8]) {
  const unsigned char* ab = smem + H * 65536 + n * 128 + ((hi ^ (n & 3)) << 3);
  const int nh = n >> 2;
  const unsigned char* bk0 = ab + ((0 ^ nh) << 5);
  const unsigned char* bk1 = ab + ((1 ^ nh) << 5);
  const unsigned char* bk2 = ab + ((2 ^ nh) << 5);
  const unsigned char* bk3 = ab + ((3 ^ nh) << 5);
  const float* eb = esqmLds + H * 512 + hi * 4;
#pragma unroll
  for (int g = 0; g < 16; ++g) {
    const int off = g * 4096;
    f32x4 e0 = *(const f32x4*)(eb + g * 32);
    f32x4 e1 = *(const f32x4*)(eb + g * 32 + 16);
    long long t0 = *(const long long*)(bk0 + off);
    long long t1 = *(const long long*)(bk1 + off);
    long long t2 = *(const long long*)(bk2 + off);
    long long t3 = *(const long long*)(bk3 + off);
    long long u0 = *(const long long*)(bk0 + off + 2048);
    long long u1 = *(const long long*)(bk1 + off + 2048);
    long long u2 = *(const long long*)(bk2 + off + 2048);
    long long u3 = *(const long long*)(bk3 + off + 2048);
    // 4 independent 4-deep MFMA chains (first mfma consumes e-init, no copies)
    f32x4 a0 = mfma8(t0, f.b0[0], e0);
    f32x4 a1 = mfma8(u0, f.b0[0], e1);
    f32x4 a2 = mfma8(t0, f.b1[0], e0);
    f32x4 a3 = mfma8(u0, f.b1[0], e1);
    a0 = mfma8(t1, f.b0[1], a0); a1 = mfma8(u1, f.b0[1], a1);
    a2 = mfma8(t1, f.b1[1], a2); a3 = mfma8(u1, f.b1[1], a3);
    a0 = mfma8(t2, f.b0[2], a0); a1 = mfma8(u2, f.b0[2], a1);
    a2 = mfma8(t2, f.b1[2], a2); a3 = mfma8(u2, f.b1[2], a3);
    a0 = mfma8(t3, f.b0[3], a0); a1 = mfma8(u3, f.b0[3], a1);
    a2 = mfma8(t3, f.b1[3], a2); a3 = mfma8(u3, f.b1[3], a3);

    const unsigned orv = (unsigned)(H * 512 + g * 32);   // group bits: OR once after pool
    {   // set 0
      float k0 = andor(a0[0], c8[0]), k1 = andor(a0[1], c8[1]);
      float k2 = andor(a0[2], c8[2]), k3 = andor(a0[3], c8[3]);
      float k4 = andor(a1[0], c8[4]), k5 = andor(a1[1], c8[5]);
      float k6 = andor(a1[2], c8[6]), k7 = andor(a1[3], c8[7]);
      float m0 = fmaxf(fmaxf(k0, k1), k2);     // max3-fusable
      float m1 = fmaxf(fmaxf(k3, k4), k5);
      float m2 = fmaxf(fmaxf(k6, k7), m0);
      float x = fmaxf(m1, m2);
      x = __builtin_bit_cast(float, __builtin_bit_cast(unsigned, x) | orv);
      ins8(top0, x);
    }
    {   // set 1
      float k0 = andor(a2[0], c8[0]), k1 = andor(a2[1], c8[1]);
      float k2 = andor(a2[2], c8[2]), k3 = andor(a2[3], c8[3]);
      float k4 = andor(a3[0], c8[4]), k5 = andor(a3[1], c8[5]);
      float k6 = andor(a3[2], c8[6]), k7 = andor(a3[3], c8[7]);
      float m0 = fmaxf(fmaxf(k0, k1), k2);
      float m1 = fmaxf(fmaxf(k3, k4), k5);
      float m2 = fmaxf(fmaxf(k6, k7), m0);
      float x = fmaxf(m1, m2);
      x = __builtin_bit_cast(float, __builtin_bit_cast(unsigned, x) | orv);
      ins8(top1, x);
    }
  }
}

// ---- main: 1 block/CU (512 thr), split codebook DMA (h2 hidden under scan h1) ----
__global__ __launch_bounds__(512, 1) void vq_main(
    const float* __restrict__ lat, const float* __restrict__ emb,
    const int* __restrict__ ksel, const unsigned char* __restrict__ ebf8,
    const float* __restrict__ esqm, float* __restrict__ out,
    unsigned long long* __restrict__ lossAcc, unsigned* __restrict__ cnt,
    float* __restrict__ loss) {
  __shared__ __align__(16) unsigned char smem[131072 + 4096 + 64];
  float* esqmLds = (float*)(smem + 131072);
  float* wLds    = (float*)(smem + 131072 + 4096);

  const int tid = threadIdx.x, lane = tid & 63, wid = tid >> 6;   // wid 0..7
  const int n = lane & 15, hi = lane >> 4;
  const int gR0 = blockIdx.x * 256;

  // (1) issue h1 DMA (codes 0..511, 64 KB) + all norms
  {
    const char* src = (const char*)ebf8 + tid * 16;
    char* dst = (char*)smem + tid * 16;
#pragma unroll
    for (int q = 0; q < 8; ++q) gload16(src + q * 8192, dst + q * 8192);
    if (tid < 256) gload16((const char*)esqm + tid * 16, (char*)esqmLds + tid * 16);
  }
  // (2) latent loads + fp8 frags + exact ||f||^2 (overlaps h1 DMA)
  Frags f = make_frags(lat, gR0 + wid * 32, gR0 + wid * 32 + 16, n, hi);
  asm volatile("s_waitcnt vmcnt(0)" ::: "memory");   // h1 + norms + latents all landed
  __builtin_amdgcn_s_barrier();

  // (3) issue h2 DMA (codes 512..1023) — lands during scan of h1
  {
    const char* src = (const char*)ebf8 + 65536 + tid * 16;
    char* dst = (char*)smem + 65536 + tid * 16;
#pragma unroll
    for (int q = 0; q < 8; ++q) gload16(src + q * 8192, dst + q * 8192);
  }

  int c8[8];   // within-group lane ids (bits 0-4); disjoint from group bits >=5
#pragma unroll
  for (int r = 0; r < 4; ++r) { c8[r] = hi * 4 + r; c8[4 + r] = 16 + hi * 4 + r; }

  const float NINF = __builtin_bit_cast(float, 0xFF800000u);
  float top0[8], top1[8];
#pragma unroll
  for (int p = 0; p < 8; ++p) { top0[p] = NINF; top1[p] = NINF; }

  scan_half<0>(smem, esqmLds, n, hi, f, c8, top0, top1);

  asm volatile("s_waitcnt vmcnt(0)" ::: "memory");   // my h2 portion landed
  __builtin_amdgcn_s_barrier();                      // everyone's h2 landed

  scan_half<1>(smem, esqmLds, n, hi, f, c8, top0, top1);

  int kk = ksel[lane & 7]; kk = kk < 0 ? 0 : (kk > 7 ? 7 : kk);

  // set 0: combine hi-lanes, pick k-th, write rows
  merge8(top0, 16); merge8(top0, 32);
  float sel0 = top0[0];
#pragma unroll
  for (int p = 1; p < 8; ++p) sel0 = (kk == p) ? top0[p] : sel0;
  unsigned sb0 = __builtin_bit_cast(unsigned, sel0);
  int idx0 = (int)(sb0 & 1023u);
  float rl0 = f.fsq0 - __builtin_bit_cast(float, sb0 & 0xFFFFFC00u) * (1.0f / 512.0f);
  write_rows(emb, out, gR0 + wid * 32, idx0, lane);

  // set 1
  merge8(top1, 16); merge8(top1, 32);
  float sel1 = top1[0];
#pragma unroll
  for (int p = 1; p < 8; ++p) sel1 = (kk == p) ? top1[p] : sel1;
  unsigned sb1 = __builtin_bit_cast(unsigned, sel1);
  int idx1 = (int)(sb1 & 1023u);
  float rl1 = f.fsq1 - __builtin_bit_cast(float, sb1 & 0xFFFFFC00u) * (1.0f / 512.0f);
  write_rows(emb, out, gR0 + wid * 32 + 16, idx1, lane);

  // deterministic loss: per-block double sum -> fixed-point int64 atomic;
  // last block converts (integer adds associative -> replay-stable)
  float c = (lane < 16) ? (rl0 + rl1) : 0.f;
#pragma unroll
  for (int m = 1; m <= 32; m <<= 1) c += __shfl_xor(c, m);
  if (lane == 0) wLds[wid] = c;
  __syncthreads();
  if (tid == 0) {
    double bs = 0.0;
#pragma unroll
    for (int w = 0; w < 8; ++w) bs += (double)wLds[w];
    long long iv = (long long)(bs * 1048576.0 + 0.5);
    atomicAdd(lossAcc, (unsigned long long)iv);
    __threadfence();
    unsigned done = atomicAdd(cnt, 1u);
    if (done == 255u) {
      unsigned long long tot = atomicAdd(lossAcc, 0ULL);
      loss[0] = (float)((double)(long long)tot * (1.25 / (1048576.0 * 8388608.0)));
    }
  }
}

extern "C" void kernel_launch(void* const* d_in, const int* in_sizes, int n_in,
                              void* d_out, int out_size, void* d_ws, size_t ws_size,
                              hipStream_t stream) {
  const float* lat = (const float*)d_in[0];   // [8192,1024] fp32
  const float* emb = (const float*)d_in[1];   // [1024,128]  fp32
  const int* ksel = (const int*)d_in[2];      // [8] int32
  float* out = (float*)d_out;                 // quantized[8388608] + loss[1]

  unsigned char* ebf8 = (unsigned char*)d_ws;                 // 131072 B swizzled fp8 codes
  float* esqm = (float*)((char*)d_ws + 131072);               // 4096 B (-512*||e||^2)
  unsigned long long* lossAcc =
      (unsigned long long*)((char*)d_ws + 135168);            // 8 B fixed-point loss
  unsigned* cnt = (unsigned*)((char*)d_ws + 135176);          // 4 B block counter

  vq_prep<<<1024, 128, 0, stream>>>(emb, ebf8, esqm, lossAcc, cnt);
  vq_main<<<256, 512, 0, stream>>>(lat, emb, ksel, ebf8, esqm, out, lossAcc, cnt,
                                   out + NELEM);
}

// Round 17
// 42.803 us; speedup vs baseline: 9.8713x; 1.2133x over previous
//
#include <hip/hip_runtime.h>

#define KDIM   128
#define NELEM  8388608

typedef __attribute__((ext_vector_type(4))) float f32x4;
typedef __attribute__((ext_vector_type(2))) int   int2v;

__device__ inline f32x4 mfma8(long long a, long long b, f32x4 c) {
  return __builtin_amdgcn_mfma_f32_16x16x32_fp8_fp8(a, b, c, 0, 0, 0);
}
__device__ inline void gload16(const void* g, void* l) {
  __builtin_amdgcn_global_load_lds(
      (const __attribute__((address_space(1))) unsigned*)g,
      (__attribute__((address_space(3))) unsigned*)l, 16, 0, 0);
}
__device__ inline long long pk8(float4 v0, float4 v1) {   // 8 fp32 -> 8 fp8 e4m3 (RNE)
  int lo = __builtin_amdgcn_cvt_pk_fp8_f32(v0.x, v0.y, 0, false);
  lo     = __builtin_amdgcn_cvt_pk_fp8_f32(v0.z, v0.w, lo, true);
  int hi = __builtin_amdgcn_cvt_pk_fp8_f32(v1.x, v1.y, 0, false);
  hi     = __builtin_amdgcn_cvt_pk_fp8_f32(v1.z, v1.w, hi, true);
  int2v t; t.x = lo; t.y = hi;
  return __builtin_bit_cast(long long, t);
}
// forced single-op (score & 0xFFFFFC00) | lo5   -- v_and_or_b32
__device__ inline float and_or10(float s, int lo5, unsigned mask) {
  float r;
  asm("v_and_or_b32 %0, %1, %2, %3" : "=v"(r) : "v"(s), "s"(mask), "v"(lo5));
  return r;
}
__device__ inline float max3f(float a, float b, float c) {
  float r;
  asm("v_max3_f32 %0, %1, %2, %3" : "=v"(r) : "v"(a), "v"(b), "v"(c));
  return r;
}
__device__ inline float sumsq(float4 a, float4 b) {
  return a.x*a.x + a.y*a.y + a.z*a.z + a.w*a.w + b.x*b.x + b.y*b.y + b.z*b.z + b.w*b.w;
}
__device__ inline void merge8(float (&t)[8], int msk) {   // bitonic top-8 of 16 across lanes
  float o[8];
#pragma unroll
  for (int p = 0; p < 8; ++p) o[p] = __shfl_xor(t[p], msk);
  float m[8];
#pragma unroll
  for (int p = 0; p < 8; ++p) m[p] = fmaxf(t[p], o[7 - p]);
#pragma unroll
  for (int s = 4; s; s >>= 1)
#pragma unroll
    for (int i = 0; i < 8; ++i)
      if (!(i & s)) {
        float x = fmaxf(m[i], m[i | s]);
        m[i | s] = fminf(m[i], m[i | s]);
        m[i] = x;
      }
#pragma unroll
  for (int p = 0; p < 8; ++p) t[p] = m[p];
}
__device__ inline void ins8(float (&top)[8], float x) {   // branchless desc top-8 insert
#pragma unroll
  for (int p = 0; p < 8; ++p) {
    float mx = fmaxf(top[p], x);
    x = fminf(top[p], x);
    top[p] = mx;
  }
}

// ---- prep: emb -> fp8 (x1024, K-XOR-swizzled) + -512*||e||^2 + zero accumulators ----
__global__ void vq_prep(const float* __restrict__ emb, unsigned char* __restrict__ ebf8,
                        float* __restrict__ esqm, unsigned long long* __restrict__ lossAcc,
                        unsigned* __restrict__ cnt) {
  int j = blockIdx.x, d = threadIdx.x;
  float v = emb[j * KDIM + d];
  float vs = v * 1024.0f;
  int p = __builtin_amdgcn_cvt_pk_fp8_f32(vs, vs, 0, false);
  ebf8[j * KDIM + (d ^ ((j & 15) << 3))] = (unsigned char)(p & 0xFF);
  float s = v * v;
#pragma unroll
  for (int m = 1; m <= 32; m <<= 1) s += __shfl_xor(s, m);
  __shared__ float w[2];
  if ((d & 63) == 0) w[d >> 6] = s;
  __syncthreads();
  if (d == 0) esqm[j] = -512.0f * (w[0] + w[1]);   // score = 1024*(f.e - ||e||^2/2)
  if (j == 0 && d == 0) { lossAcc[0] = 0ULL; cnt[0] = 0u; }
}

__device__ inline void write_rows(const float* __restrict__ emb, float* __restrict__ outp,
                                  int grow0, int idx, int lane) {
#pragma unroll 4
  for (int r = 0; r < 16; ++r) {
    int s2 = __shfl(idx, r);
    float2 qv = *(const float2*)(emb + (size_t)s2 * KDIM + lane * 2);
    *(float2*)(outp + (size_t)(grow0 + r) * KDIM + lane * 2) = qv;
  }
}

// ---- main: 1 block/CU (512 thr, 8 waves), 32 rows/wave, forced-op select ----
__global__ __launch_bounds__(512, 1) void vq_main(
    const float* __restrict__ lat, const float* __restrict__ emb,
    const int* __restrict__ ksel, const unsigned char* __restrict__ ebf8,
    const float* __restrict__ esqm, float* __restrict__ out,
    unsigned long long* __restrict__ lossAcc, unsigned* __restrict__ cnt,
    float* __restrict__ loss) {
  __shared__ __align__(16) unsigned char smem[131072 + 4096 + 64];
  float* esqmLds = (float*)(smem + 131072);
  float* wLds    = (float*)(smem + 131072 + 4096);

  const int tid = threadIdx.x, lane = tid & 63, wid = tid >> 6;   // wid 0..7
  const int n = lane & 15, hi = lane >> 4;
  const int gR0 = blockIdx.x * 256;

  // (a) row-set 0 (wid*32 + 0..15) and row-set 1 (+16) -> issue loads
  const float* rp0 = lat + (size_t)(gR0 + wid * 32 + n) * KDIM + hi * 8;
  const float* rp1 = rp0 + 16 * KDIM;
  float4 p0[4], p1[4], q0[4], q1[4];
#pragma unroll
  for (int ks = 0; ks < 4; ++ks) {
    p0[ks] = *(const float4*)(rp0 + ks * 32);
    p1[ks] = *(const float4*)(rp0 + ks * 32 + 4);
    q0[ks] = *(const float4*)(rp1 + ks * 32);
    q1[ks] = *(const float4*)(rp1 + ks * 32 + 4);
  }
  // (b) codebook (128 KB) + norms (4 KB) DMA -> LDS (pre-swizzled; linear copy)
  {
    const char* src = (const char*)ebf8 + tid * 16;
    char* dst = (char*)smem + tid * 16;
#pragma unroll
    for (int qq = 0; qq < 16; ++qq) gload16(src + qq * 8192, dst + qq * 8192);
    if (tid < 256) gload16((const char*)esqm + tid * 16, (char*)esqmLds + tid * 16);
  }
  // (c) frags (fp8) + exact ||f||^2 per set
  float fsq0, fsq1;
  long long b00, b01, b02, b03, b10, b11, b12, b13;
  {
    float s0 = 0.f, s1 = 0.f;
#pragma unroll
    for (int ks = 0; ks < 4; ++ks) {
      s0 += sumsq(p0[ks], p1[ks]);
      s1 += sumsq(q0[ks], q1[ks]);
    }
    s0 += __shfl_xor(s0, 16); s0 += __shfl_xor(s0, 32);
    s1 += __shfl_xor(s1, 16); s1 += __shfl_xor(s1, 32);
    fsq0 = s0; fsq1 = s1;
    b00 = pk8(p0[0], p1[0]); b01 = pk8(p0[1], p1[1]);
    b02 = pk8(p0[2], p1[2]); b03 = pk8(p0[3], p1[3]);
    b10 = pk8(q0[0], q1[0]); b11 = pk8(q0[1], q1[1]);
    b12 = pk8(q0[2], q1[2]); b13 = pk8(q0[3], q1[3]);
  }
  asm volatile("s_waitcnt vmcnt(0)" ::: "memory");
  __builtin_amdgcn_s_barrier();

  // A-read addressing: byte = row*128 + ((ks*32+hi*8) ^ ((row&15)<<3))
  const unsigned char* ab = smem + n * 128 + ((hi ^ (n & 3)) << 3);
  const int nh = n >> 2;
  const unsigned char* bk0 = ab + ((0 ^ nh) << 5);
  const unsigned char* bk1 = ab + ((1 ^ nh) << 5);
  const unsigned char* bk2 = ab + ((2 ^ nh) << 5);
  const unsigned char* bk3 = ab + ((3 ^ nh) << 5);

  // per-lane 5-bit index constants (u*16 + hi*4 + r), fixed across groups
  int c8[8];
#pragma unroll
  for (int r = 0; r < 4; ++r) { c8[r] = hi * 4 + r; c8[4 + r] = 16 + hi * 4 + r; }
  const unsigned MASK = 0xFFFFFC00u;

  const float NINF = __builtin_bit_cast(float, 0xFF800000u);
  float top0[8], top1[8];
#pragma unroll
  for (int p = 0; p < 8; ++p) { top0[p] = NINF; top1[p] = NINF; }

#pragma unroll 4
  for (int g = 0; g < 32; ++g) {
    const int off = g * 4096;
    const float* eb = esqmLds + g * 32 + hi * 4;
    f32x4 e0 = *(const f32x4*)(eb);
    f32x4 e1 = *(const f32x4*)(eb + 16);
    long long t0 = *(const long long*)(bk0 + off);
    long long t1 = *(const long long*)(bk1 + off);
    long long t2 = *(const long long*)(bk2 + off);
    long long t3 = *(const long long*)(bk3 + off);
    long long u0 = *(const long long*)(bk0 + off + 2048);
    long long u1 = *(const long long*)(bk1 + off + 2048);
    long long u2 = *(const long long*)(bk2 + off + 2048);
    long long u3 = *(const long long*)(bk3 + off + 2048);
    // 4 independent 4-deep MFMA chains (2 row-sets x 2 code-subgroups)
    f32x4 a0 = mfma8(t0, b00, e0);
    f32x4 a1 = mfma8(u0, b00, e1);
    f32x4 a2 = mfma8(t0, b10, e0);
    f32x4 a3 = mfma8(u0, b10, e1);
    a0 = mfma8(t1, b01, a0); a1 = mfma8(u1, b01, a1);
    a2 = mfma8(t1, b11, a2); a3 = mfma8(u1, b11, a3);
    a0 = mfma8(t2, b02, a0); a1 = mfma8(u2, b02, a1);
    a2 = mfma8(t2, b12, a2); a3 = mfma8(u2, b12, a3);
    a0 = mfma8(t3, b03, a0); a1 = mfma8(u3, b03, a1);
    a2 = mfma8(t3, b13, a2); a3 = mfma8(u3, b13, a3);

    const unsigned orv = (unsigned)g << 5;   // group bits, OR'd once per pooled key
    {   // set 0: 8 and_or + 3 max3 + 1 max + 1 or + ins8
      float k0 = and_or10(a0[0], c8[0], MASK), k1 = and_or10(a0[1], c8[1], MASK);
      float k2 = and_or10(a0[2], c8[2], MASK), k3 = and_or10(a0[3], c8[3], MASK);
      float k4 = and_or10(a1[0], c8[4], MASK), k5 = and_or10(a1[1], c8[5], MASK);
      float k6 = and_or10(a1[2], c8[6], MASK), k7 = and_or10(a1[3], c8[7], MASK);
      float m0 = max3f(k0, k1, k2);
      float m1 = max3f(k3, k4, k5);
      float m2 = max3f(k6, k7, m0);
      float x = fmaxf(m1, m2);
      x = __builtin_bit_cast(float, __builtin_bit_cast(unsigned, x) | orv);
      ins8(top0, x);
    }
    {   // set 1
      float k0 = and_or10(a2[0], c8[0], MASK), k1 = and_or10(a2[1], c8[1], MASK);
      float k2 = and_or10(a2[2], c8[2], MASK), k3 = and_or10(a2[3], c8[3], MASK);
      float k4 = and_or10(a3[0], c8[4], MASK), k5 = and_or10(a3[1], c8[5], MASK);
      float k6 = and_or10(a3[2], c8[6], MASK), k7 = and_or10(a3[3], c8[7], MASK);
      float m0 = max3f(k0, k1, k2);
      float m1 = max3f(k3, k4, k5);
      float m2 = max3f(k6, k7, m0);
      float x = fmaxf(m1, m2);
      x = __builtin_bit_cast(float, __builtin_bit_cast(unsigned, x) | orv);
      ins8(top1, x);
    }
  }

  int kk = ksel[lane & 7];                 // row&7 == n&7 == lane&7 for both sets
  kk = kk < 0 ? 0 : (kk > 7 ? 7 : kk);

  // set 0: combine hi-lanes, pick k-th, write rows
  merge8(top0, 16); merge8(top0, 32);
  float sel0 = top0[0];
#pragma unroll
  for (int p = 1; p < 8; ++p) sel0 = (kk == p) ? top0[p] : sel0;
  unsigned sb0 = __builtin_bit_cast(unsigned, sel0);
  int idx0 = (int)(sb0 & 1023u);
  float rl0 = fsq0 - __builtin_bit_cast(float, sb0 & 0xFFFFFC00u) * (1.0f / 512.0f);
  write_rows(emb, out, gR0 + wid * 32, idx0, lane);

  // set 1
  merge8(top1, 16); merge8(top1, 32);
  float sel1 = top1[0];
#pragma unroll
  for (int p = 1; p < 8; ++p) sel1 = (kk == p) ? top1[p] : sel1;
  unsigned sb1 = __builtin_bit_cast(unsigned, sel1);
  int idx1 = (int)(sb1 & 1023u);
  float rl1 = fsq1 - __builtin_bit_cast(float, sb1 & 0xFFFFFC00u) * (1.0f / 512.0f);
  write_rows(emb, out, gR0 + wid * 32 + 16, idx1, lane);

  // deterministic loss: per-block double sum -> fixed-point int64 atomic;
  // last block converts (integer adds associative -> replay-stable)
  float c = (lane < 16) ? (rl0 + rl1) : 0.f;
#pragma unroll
  for (int m = 1; m <= 32; m <<= 1) c += __shfl_xor(c, m);
  if (lane == 0) wLds[wid] = c;
  __syncthreads();
  if (tid == 0) {
    double bs = 0.0;
#pragma unroll
    for (int w = 0; w < 8; ++w) bs += (double)wLds[w];
    long long iv = (long long)(bs * 1048576.0 + 0.5);
    atomicAdd(lossAcc, (unsigned long long)iv);
    __threadfence();
    unsigned done = atomicAdd(cnt, 1u);
    if (done == 255u) {
      unsigned long long tot = atomicAdd(lossAcc, 0ULL);
      loss[0] = (float)((double)(long long)tot * (1.25 / (1048576.0 * 8388608.0)));
    }
  }
}

extern "C" void kernel_launch(void* const* d_in, const int* in_sizes, int n_in,
                              void* d_out, int out_size, void* d_ws, size_t ws_size,
                              hipStream_t stream) {
  const float* lat = (const float*)d_in[0];   // [8192,1024] fp32
  const float* emb = (const float*)d_in[1];   // [1024,128]  fp32
  const int* ksel = (const int*)d_in[2];      // [8] int32
  float* out = (float*)d_out;                 // quantized[8388608] + loss[1]

  unsigned char* ebf8 = (unsigned char*)d_ws;                 // 131072 B swizzled fp8 codes
  float* esqm = (float*)((char*)d_ws + 131072);               // 4096 B (-512*||e||^2)
  unsigned long long* lossAcc =
      (unsigned long long*)((char*)d_ws + 135168);            // 8 B fixed-point loss
  unsigned* cnt = (unsigned*)((char*)d_ws + 135176);          // 4 B block counter

  vq_prep<<<1024, 128, 0, stream>>>(emb, ebf8, esqm, lossAcc, cnt);
  vq_main<<<256, 512, 0, stream>>>(lat, emb, ksel, ebf8, esqm, out, lossAcc, cnt,
                                   out + NELEM);
}